// Round 7
// baseline (955.206 us; speedup 1.0000x reference)
//
#include <hip/hip_runtime.h>
#include <hip/hip_bf16.h>

#define BATCH   16
#define NPTS    4096
#define CIN     256
#define COUT    512
#define KNN     16
#define NOUT    1024
#define XOUT_ELEMS 8388608   // 16*1024*512
#define LDA     40           // padded LDS leading dim (bf16 elems), known-good
#define DYN_LDS 53408        // 49152 xyz + 64 keys + 96 coords + 4096 wins

typedef __attribute__((ext_vector_type(4))) float f32x4;
typedef __attribute__((ext_vector_type(2))) float f32x2;
typedef __attribute__((ext_vector_type(8))) short bf16x8;
typedef unsigned long long u64;

__device__ __forceinline__ unsigned short f2bf_rne(float f) {
    unsigned u = __float_as_uint(f);
    return (unsigned short)((u + 0x7FFFu + ((u >> 16) & 1u)) >> 16);
}
__device__ __forceinline__ float bf2f(unsigned short s) {
    return __uint_as_float(((unsigned)s) << 16);
}

// 6-step DPP max-reduce across 64 lanes; lane 63 ends with the max (HW-validated R1).
__device__ __forceinline__ float wave_max_dpp(float v) {
    int x, y;
    x = __float_as_int(v);
    y = __builtin_amdgcn_update_dpp(x, x, 0x111, 0xf, 0xf, false);
    v = fmaxf(v, __int_as_float(y)); x = __float_as_int(v);
    y = __builtin_amdgcn_update_dpp(x, x, 0x112, 0xf, 0xf, false);
    v = fmaxf(v, __int_as_float(y)); x = __float_as_int(v);
    y = __builtin_amdgcn_update_dpp(x, x, 0x114, 0xf, 0xf, false);
    v = fmaxf(v, __int_as_float(y)); x = __float_as_int(v);
    y = __builtin_amdgcn_update_dpp(x, x, 0x118, 0xf, 0xf, false);
    v = fmaxf(v, __int_as_float(y)); x = __float_as_int(v);
    y = __builtin_amdgcn_update_dpp(x, x, 0x142, 0xf, 0xf, false);
    v = fmaxf(v, __int_as_float(y)); x = __float_as_int(v);
    y = __builtin_amdgcn_update_dpp(x, x, 0x143, 0xf, 0xf, false);
    v = fmaxf(v, __int_as_float(y));
    return v;
}

// Kernel 1: blocks [0,16) FPS (R6 structure + single-LDS-round-trip winner
// publication: lead lane writes key AND candidate coords, extracted from
// registers via constant-index cndmask tree); blocks [16,2064) GEMM.
extern "C" __global__ void __launch_bounds__(256)
fps_gemm(const float* __restrict__ x, const float* __restrict__ p,
         const float* __restrict__ W, const float* __restrict__ bias,
         const float* __restrict__ gamma, const float* __restrict__ beta,
         const float* __restrict__ rmean, const float* __restrict__ rvar,
         int* __restrict__ fid, unsigned short* __restrict__ h,
         float* __restrict__ out)
{
    extern __shared__ char smem[];
    const int t = threadIdx.x;
    const int lane = t & 63;
    const int wv = t >> 6;

    if (blockIdx.x < BATCH) {
        // ---------------- FPS: exact replica of numpy f32 arithmetic ----------------
#pragma clang fp contract(off)
        const int b = blockIdx.x;
        float* lx = (float*)smem;                        // [4096]
        float* ly = lx + NPTS;
        float* lz = ly + NPTS;
        u64*   warr = (u64*)(smem + 49152);              // [2][4] parity dbuf keys
        float* wcx  = (float*)(smem + 49216);            // [2][4] candidate coords
        float* wcy  = (float*)(smem + 49248);
        float* wcz  = (float*)(smem + 49280);
        int*   wins = (int*)(smem + 49312);              // [1024] winner indices
        float* pout = out + XOUT_ELEMS + (size_t)b * NOUT * 3;

        const float* pb = p + (size_t)b * NPTS * 3;
        for (int l = t; l < NPTS * 3; l += 256) {
            float v = pb[l];
            int pi = l / 3;
            int c = l - pi * 3;
            if (c == 0) lx[pi] = v; else if (c == 1) ly[pi] = v; else lz[pi] = v;
        }
        if (t == 0) wins[0] = 0;       // idxs[0] = 0
        __syncthreads();

        // thread t owns points [16t,16t+16): lowest lane == lowest point index,
        // so ballot+ctz reproduces np.argmax first-occurrence exactly.
        f32x2 px2[8], py2[8], pz2[8], d2[8];
        const int base = t << 4;
#pragma unroll
        for (int j = 0; j < 8; ++j) {
            px2[j] = *(const f32x2*)(lx + base + (j << 1));
            py2[j] = *(const f32x2*)(ly + base + (j << 1));
            pz2[j] = *(const f32x2*)(lz + base + (j << 1));
            d2[j]  = (f32x2){3.4028235e38f, 3.4028235e38f}; // min(FLT_MAX,d0)==d0
        }

        float wx = lx[0], wy = ly[0], wz = lz[0];        // winner(0) = point 0
        for (int i = 1; i < NOUT; ++i) {
            f32x2 wx2 = {wx, wx}, wy2 = {wy, wy}, wz2 = {wz, wz};
            // split accumulators (R4-correctness-proven): chain A owns elements
            // 0..7, chain B owns 8..15 -> argmax dep chain halved.
            float bdA = -1.0f, bdB = -1.0f;
            int   bjA = 0,     bjB = 8;
#pragma unroll
            for (int j = 0; j < 4; ++j) {
                // np semantics: ((dx*dx + dy*dy) + dz*dz), RN, no fma (contract off)
                f32x2 dx = px2[j] - wx2;
                f32x2 dy = py2[j] - wy2;
                f32x2 dz = pz2[j] - wz2;
                f32x2 s  = ((dx * dx) + (dy * dy)) + (dz * dz);
                f32x2 nd;
                nd.x = fminf(d2[j].x, s.x);
                nd.y = fminf(d2[j].y, s.y);
                d2[j] = nd;
                bool g0 = nd.x > bdA;            // strict >: earliest idx wins
                bdA = g0 ? nd.x : bdA;
                bjA = g0 ? (j << 1) : bjA;
                bool g1 = nd.y > bdA;
                bdA = g1 ? nd.y : bdA;
                bjA = g1 ? (j << 1) + 1 : bjA;
            }
#pragma unroll
            for (int j = 4; j < 8; ++j) {
                f32x2 dx = px2[j] - wx2;
                f32x2 dy = py2[j] - wy2;
                f32x2 dz = pz2[j] - wz2;
                f32x2 s  = ((dx * dx) + (dy * dy)) + (dz * dz);
                f32x2 nd;
                nd.x = fminf(d2[j].x, s.x);
                nd.y = fminf(d2[j].y, s.y);
                d2[j] = nd;
                bool g0 = nd.x > bdB;
                bdB = g0 ? nd.x : bdB;
                bjB = g0 ? (j << 1) : bjB;
                bool g1 = nd.y > bdB;
                bdB = g1 ? nd.y : bdB;
                bjB = g1 ? (j << 1) + 1 : bjB;
            }
            // merge: A holds earlier indices -> strict > keeps first occurrence
            bool gm = bdB > bdA;
            float bestd = gm ? bdB : bdA;
            int   bestj = gm ? bjB : bjA;
            // Candidate-coord extract from registers: constant-index cndmask
            // tree (no dynamic reg indexing -> no scratch, R5 lesson). These
            // ~48 VALU ops are independent of the DPP chain below and
            // interleave into its latency.
            const int j2 = bestj >> 1;
            const bool s0b = (j2 & 1) != 0, s1b = (j2 & 2) != 0,
                       s2b = (j2 & 4) != 0, odd = (bestj & 1) != 0;
            f32x2 ex0 = s0b ? px2[1] : px2[0], ex1 = s0b ? px2[3] : px2[2];
            f32x2 ex2 = s0b ? px2[5] : px2[4], ex3 = s0b ? px2[7] : px2[6];
            f32x2 ey0 = s0b ? py2[1] : py2[0], ey1 = s0b ? py2[3] : py2[2];
            f32x2 ey2 = s0b ? py2[5] : py2[4], ey3 = s0b ? py2[7] : py2[6];
            f32x2 ez0 = s0b ? pz2[1] : pz2[0], ez1 = s0b ? pz2[3] : pz2[2];
            f32x2 ez2 = s0b ? pz2[5] : pz2[4], ez3 = s0b ? pz2[7] : pz2[6];
            f32x2 exa = s1b ? ex1 : ex0, exb = s1b ? ex3 : ex2;
            f32x2 eya = s1b ? ey1 : ey0, eyb = s1b ? ey3 : ey2;
            f32x2 eza = s1b ? ez1 : ez0, ezb = s1b ? ez3 : ez2;
            f32x2 exf = s2b ? exb : exa;
            f32x2 eyf = s2b ? eyb : eya;
            f32x2 ezf = s2b ? ezb : eza;
            float bx = odd ? exf.y : exf.x;
            float by = odd ? eyf.y : eyf.x;
            float bz = odd ? ezf.y : ezf.x;
            // wave argmax (value via DPP, first-lane tie-break via ballot)
            float vmax = wave_max_dpp(bestd);
            float wmax = __int_as_float(
                __builtin_amdgcn_readlane(__float_as_int(vmax), 63));
            u64 msk = __ballot(bestd == wmax);
            int lead = (int)__builtin_ctzll(msk);
            int wbpi = __builtin_amdgcn_readlane(base + bestj, lead);
            // d>=0: f32 bits order-isomorphic as unsigned; low word prefers
            // LOWEST point index on cross-wave ties. Lead lane publishes key
            // AND its candidate's coords -> ONE LDS round trip per iteration.
            const int row = ((i & 1) << 2) + wv;         // parity dbuf
            if (lane == lead) {
                warr[row] = ((u64)__float_as_uint(wmax) << 32)
                          | (unsigned)(NPTS - 1 - wbpi);
                wcx[row] = bx; wcy[row] = by; wcz[row] = bz;
            }
            __syncthreads();                   // LDS-only traffic: cheap drain
            const int r0 = (i & 1) << 2;
            // 5 parallel b128 reads -> one latency window; depth-2 tree select
            // on keys steers coords via the same predicates.
            ulonglong2 q01 = *(const ulonglong2*)(warr + r0);
            ulonglong2 q23 = *(const ulonglong2*)(warr + r0 + 2);
            float4 cx4 = *(const float4*)(wcx + r0);
            float4 cy4 = *(const float4*)(wcy + r0);
            float4 cz4 = *(const float4*)(wcz + r0);
            bool g1 = q01.y > q01.x;
            u64 kA = g1 ? q01.y : q01.x;
            float xA = g1 ? cx4.y : cx4.x, yA = g1 ? cy4.y : cy4.x,
                  zA = g1 ? cz4.y : cz4.x;
            bool g2 = q23.y > q23.x;
            u64 kB = g2 ? q23.y : q23.x;
            float xB = g2 ? cx4.w : cx4.z, yB = g2 ? cy4.w : cy4.z,
                  zB = g2 ? cz4.w : cz4.z;
            bool g3 = kB > kA;
            u64 k0 = g3 ? kB : kA;
            wx = g3 ? xB : xA; wy = g3 ? yB : yA; wz = g3 ? zB : zA;
            if (t == 0)
                wins[i] = NPTS - 1 - (int)(unsigned)(k0 & 0xffffffffull);
        }
        // epilogue: bulk-write fid and p_out (off the per-iteration critical path)
        __syncthreads();
        for (int i = t; i < NOUT; i += 256) {
            int w = wins[i];
            fid[b * NOUT + i] = b * NPTS + w;
            float* po = pout + (size_t)i * 3;
            po[0] = lx[w]; po[1] = ly[w]; po[2] = lz[w];
        }
    } else {
        // ---------------- GEMM: h = relu(BN(x @ W^T + b)), bf16 MFMA ----------------
        const int bid = blockIdx.x - BATCH;
        const int bm = bid >> 2;           // 512 M-tiles of 128
        const int bn = bid & 3;            // 4 N-tiles of 128
        short* As = (short*)smem;          // [128][LDA]
        short* Bs = As + 128 * LDA;        // [128][LDA] (W is [n][k] = B^T)

        const int wm = wv >> 1, wn = wv & 1;   // 2x2 waves, 64x64 each
        const int quad = lane >> 4, l16 = lane & 15;
        const int m0 = bm * 128, n0 = bn * 128;

        f32x4 acc[4][4];
        const f32x4 zero = {0.0f, 0.0f, 0.0f, 0.0f};
#pragma unroll
        for (int a = 0; a < 4; ++a)
#pragma unroll
            for (int bb = 0; bb < 4; ++bb) acc[a][bb] = zero;

        const int srow = t >> 3;           // 0..31
        const int scol = (t & 7) << 2;     // 0..28

        for (int ks = 0; ks < 8; ++ks) {   // K=256 in steps of 32
            const int k0 = ks * 32;
            __syncthreads();
#pragma unroll
            for (int it = 0; it < 4; ++it) {
                int row = srow + it * 32;
                float4 va = *(const float4*)(x + (size_t)(m0 + row) * CIN + k0 + scol);
                short4 pa = make_short4((short)f2bf_rne(va.x), (short)f2bf_rne(va.y),
                                        (short)f2bf_rne(va.z), (short)f2bf_rne(va.w));
                *(short4*)(As + row * LDA + scol) = pa;
                float4 vb = *(const float4*)(W + (size_t)(n0 + row) * CIN + k0 + scol);
                short4 pb2 = make_short4((short)f2bf_rne(vb.x), (short)f2bf_rne(vb.y),
                                         (short)f2bf_rne(vb.z), (short)f2bf_rne(vb.w));
                *(short4*)(Bs + row * LDA + scol) = pb2;
            }
            __syncthreads();
            bf16x8 af[4], bfr[4];
#pragma unroll
            for (int tm = 0; tm < 4; ++tm)
                af[tm] = *(const bf16x8*)(As + (wm * 64 + tm * 16 + l16) * LDA + quad * 8);
#pragma unroll
            for (int tn = 0; tn < 4; ++tn)
                bfr[tn] = *(const bf16x8*)(Bs + (wn * 64 + tn * 16 + l16) * LDA + quad * 8);
#pragma unroll
            for (int tm = 0; tm < 4; ++tm)
#pragma unroll
                for (int tn = 0; tn < 4; ++tn)
                    acc[tm][tn] = __builtin_amdgcn_mfma_f32_16x16x32_bf16(
                        af[tm], bfr[tn], acc[tm][tn], 0, 0, 0);
        }
#pragma unroll
        for (int tn = 0; tn < 4; ++tn) {
            int c = n0 + wn * 64 + tn * 16 + l16;
            float sc = gamma[c] / sqrtf(rvar[c] + 1e-5f);
            float sh = (bias[c] - rmean[c]) * sc + beta[c];
#pragma unroll
            for (int tm = 0; tm < 4; ++tm) {
                int rbase = m0 + wm * 64 + tm * 16 + quad * 4;
#pragma unroll
                for (int r = 0; r < 4; ++r) {
                    float v = fmaxf(acc[tm][tn][r] * sc + sh, 0.0f);
                    h[(size_t)(rbase + r) * COUT + c] = f2bf_rne(v);
                }
            }
        }
    }
}

// Kernel 2: gather+maxpool (known-good R2/R7 version)
extern "C" __global__ void __launch_bounds__(128)
gather_maxpool(const int* __restrict__ sid32, const int* __restrict__ fid,
               const unsigned short* __restrict__ h, float* __restrict__ out)
{
    const int j = blockIdx.x;     // 0..16383
    const int t = threadIdx.x;
    __shared__ int rows[KNN];
    const int frow = fid[j];
    // sid_euc may be int32 or int64 (JAX x64 ambiguity); sniff high words.
    bool is64 = (sid32[1] == 0) && (sid32[3] == 0) && (sid32[5] == 0);
    if (t < KNN) {
        long long e = (long long)frow * KNN + t;
        rows[t] = is64 ? sid32[e * 2] : sid32[e];
    }
    __syncthreads();

    const int c4 = t << 2;
    float m0 = -3.4028235e38f, m1 = m0, m2 = m0, m3 = m0;
#pragma unroll
    for (int k = 0; k < KNN; ++k) {
        const ushort4 v = *(const ushort4*)(h + (size_t)rows[k] * COUT + c4);
        m0 = fmaxf(m0, bf2f(v.x));
        m1 = fmaxf(m1, bf2f(v.y));
        m2 = fmaxf(m2, bf2f(v.z));
        m3 = fmaxf(m3, bf2f(v.w));
    }
    *(float4*)(out + (size_t)j * COUT + c4) = make_float4(m0, m1, m2, m3);
}

extern "C" void kernel_launch(void* const* d_in, const int* in_sizes, int n_in,
                              void* d_out, int out_size, void* d_ws, size_t ws_size,
                              hipStream_t stream)
{
    const float* x     = (const float*)d_in[0];
    const float* p     = (const float*)d_in[1];
    const int*   sid   = (const int*)d_in[2];   // tid_euc (d_in[3]) unused
    const float* W     = (const float*)d_in[4];
    const float* bias  = (const float*)d_in[5];
    const float* gamma = (const float*)d_in[6];
    const float* beta  = (const float*)d_in[7];
    const float* rmean = (const float*)d_in[8];
    const float* rvar  = (const float*)d_in[9];
    float* out = (float*)d_out;

    int* fid = (int*)d_ws;                                      // [16384] @ 0
    unsigned short* h = (unsigned short*)((char*)d_ws + 65792); // 65536x512 bf16

    hipLaunchKernelGGL(fps_gemm, dim3(BATCH + 2048), dim3(256), DYN_LDS, stream,
                       x, p, W, bias, gamma, beta, rmean, rvar, fid, h, out);
    hipLaunchKernelGGL(gather_maxpool, dim3(BATCH * NOUT), dim3(128), 0, stream,
                       sid, fid, h, out);
}

// Round 9
// 724.326 us; speedup vs baseline: 1.3188x; 1.3188x over previous
//
#include <hip/hip_runtime.h>
#include <hip/hip_bf16.h>

#define BATCH   16
#define NPTS    4096
#define CIN     256
#define COUT    512
#define KNN     16
#define NOUT    1024
#define XOUT_ELEMS 8388608   // 16*1024*512
#define LDA     40           // padded LDS leading dim (bf16 elems), known-good
#define DYN_LDS 53312        // 3*4096*4 (xyz) + 64 (warr) + 4096 (wins)

typedef __attribute__((ext_vector_type(4))) float f32x4;
typedef __attribute__((ext_vector_type(2))) float f32x2;
typedef __attribute__((ext_vector_type(8))) short bf16x8;
typedef __attribute__((ext_vector_type(8))) unsigned short u16x8;
typedef unsigned long long u64;

__device__ __forceinline__ unsigned short f2bf_rne(float f) {
    unsigned u = __float_as_uint(f);
    return (unsigned short)((u + 0x7FFFu + ((u >> 16) & 1u)) >> 16);
}
__device__ __forceinline__ float bf2f(unsigned short s) {
    return __uint_as_float(((unsigned)s) << 16);
}

// 6-step DPP max-reduce across 64 lanes; lane 63 ends with the max (HW-validated R1).
__device__ __forceinline__ float wave_max_dpp(float v) {
    int x, y;
    x = __float_as_int(v);
    y = __builtin_amdgcn_update_dpp(x, x, 0x111, 0xf, 0xf, false);
    v = fmaxf(v, __int_as_float(y)); x = __float_as_int(v);
    y = __builtin_amdgcn_update_dpp(x, x, 0x112, 0xf, 0xf, false);
    v = fmaxf(v, __int_as_float(y)); x = __float_as_int(v);
    y = __builtin_amdgcn_update_dpp(x, x, 0x114, 0xf, 0xf, false);
    v = fmaxf(v, __int_as_float(y)); x = __float_as_int(v);
    y = __builtin_amdgcn_update_dpp(x, x, 0x118, 0xf, 0xf, false);
    v = fmaxf(v, __int_as_float(y)); x = __float_as_int(v);
    y = __builtin_amdgcn_update_dpp(x, x, 0x142, 0xf, 0xf, false);
    v = fmaxf(v, __int_as_float(y)); x = __float_as_int(v);
    y = __builtin_amdgcn_update_dpp(x, x, 0x143, 0xf, 0xf, false);
    v = fmaxf(v, __int_as_float(y));
    return v;
}

// Kernel 1: blocks [0,16) FPS (R6 version — proven best, byte-identical);
//           blocks [16,2064) GEMM.
extern "C" __global__ void __launch_bounds__(256)
fps_gemm(const float* __restrict__ x, const float* __restrict__ p,
         const float* __restrict__ W, const float* __restrict__ bias,
         const float* __restrict__ gamma, const float* __restrict__ beta,
         const float* __restrict__ rmean, const float* __restrict__ rvar,
         int* __restrict__ fid, unsigned short* __restrict__ h,
         float* __restrict__ out)
{
    extern __shared__ char smem[];
    const int t = threadIdx.x;
    const int lane = t & 63;
    const int wv = t >> 6;

    if (blockIdx.x < BATCH) {
        // ---------------- FPS: exact replica of numpy f32 arithmetic ----------------
#pragma clang fp contract(off)
        const int b = blockIdx.x;
        float* lx = (float*)smem;                        // [4096]
        float* ly = lx + NPTS;
        float* lz = ly + NPTS;
        u64* warr = (u64*)(smem + 49152);                // [2][4] parity dbuf keys
        int* wins = (int*)(smem + 49216);                // [1024] winner indices
        float* pout = out + XOUT_ELEMS + (size_t)b * NOUT * 3;

        const float* pb = p + (size_t)b * NPTS * 3;
        for (int l = t; l < NPTS * 3; l += 256) {
            float v = pb[l];
            int pi = l / 3;
            int c = l - pi * 3;
            if (c == 0) lx[pi] = v; else if (c == 1) ly[pi] = v; else lz[pi] = v;
        }
        if (t == 0) wins[0] = 0;       // idxs[0] = 0
        __syncthreads();

        // thread t owns points [16t,16t+16): lowest lane == lowest point index,
        // so ballot+ctz reproduces np.argmax first-occurrence exactly.
        f32x2 px2[8], py2[8], pz2[8], d2[8];
        const int base = t << 4;
#pragma unroll
        for (int j = 0; j < 8; ++j) {
            px2[j] = *(const f32x2*)(lx + base + (j << 1));
            py2[j] = *(const f32x2*)(ly + base + (j << 1));
            pz2[j] = *(const f32x2*)(lz + base + (j << 1));
            d2[j]  = (f32x2){3.4028235e38f, 3.4028235e38f}; // min(FLT_MAX,d0)==d0
        }

        int winner = 0;
        for (int i = 1; i < NOUT; ++i) {
            float wx = lx[winner], wy = ly[winner], wz = lz[winner]; // LDS bcast
            f32x2 wx2 = {wx, wx}, wy2 = {wy, wy}, wz2 = {wz, wz};
            // split accumulators (R4-correctness-proven): chain A owns elements
            // 0..7, chain B owns 8..15 -> argmax dep chain halved. bdB init -1
            // with any bjB: first B compare always fires (d >= 0 > -1).
            float bdA = -1.0f, bdB = -1.0f;
            int   bjA = 0,     bjB = 8;
#pragma unroll
            for (int j = 0; j < 4; ++j) {
                // np semantics: ((dx*dx + dy*dy) + dz*dz), RN, no fma (contract off)
                f32x2 dx = px2[j] - wx2;
                f32x2 dy = py2[j] - wy2;
                f32x2 dz = pz2[j] - wz2;
                f32x2 s  = ((dx * dx) + (dy * dy)) + (dz * dz);
                f32x2 nd;
                nd.x = fminf(d2[j].x, s.x);
                nd.y = fminf(d2[j].y, s.y);
                d2[j] = nd;
                bool g0 = nd.x > bdA;            // strict >: earliest idx wins
                bdA = g0 ? nd.x : bdA;
                bjA = g0 ? (j << 1) : bjA;
                bool g1 = nd.y > bdA;
                bdA = g1 ? nd.y : bdA;
                bjA = g1 ? (j << 1) + 1 : bjA;
            }
#pragma unroll
            for (int j = 4; j < 8; ++j) {
                f32x2 dx = px2[j] - wx2;
                f32x2 dy = py2[j] - wy2;
                f32x2 dz = pz2[j] - wz2;
                f32x2 s  = ((dx * dx) + (dy * dy)) + (dz * dz);
                f32x2 nd;
                nd.x = fminf(d2[j].x, s.x);
                nd.y = fminf(d2[j].y, s.y);
                d2[j] = nd;
                bool g0 = nd.x > bdB;
                bdB = g0 ? nd.x : bdB;
                bjB = g0 ? (j << 1) : bjB;
                bool g1 = nd.y > bdB;
                bdB = g1 ? nd.y : bdB;
                bjB = g1 ? (j << 1) + 1 : bjB;
            }
            // merge: A holds earlier indices -> strict > keeps first occurrence
            bool gm = bdB > bdA;
            float bestd = gm ? bdB : bdA;
            int   bestj = gm ? bjB : bjA;
            // wave argmax (value via DPP, first-lane tie-break via ballot)
            float vmax = wave_max_dpp(bestd);
            float wmax = __int_as_float(
                __builtin_amdgcn_readlane(__float_as_int(vmax), 63));
            u64 msk = __ballot(bestd == wmax);
            int lead = (int)__builtin_ctzll(msk);
            int wbpi = __builtin_amdgcn_readlane(base + bestj, lead);
            // d>=0: f32 bits order-isomorphic as unsigned; low word prefers
            // LOWEST point index on cross-wave ties.
            u64 key = ((u64)__float_as_uint(wmax) << 32)
                    | (unsigned)(NPTS - 1 - wbpi);
            u64* wrow = warr + ((i & 1) << 2);     // parity dbuf: 1 barrier/iter
            if (lane == 0) wrow[wv] = key;
            __syncthreads();                       // NO global stores pending: only
                                                   // LDS ops drain here (cheap)
            // vectorized key fetch (2x ds_read_b128) + depth-2 tree select;
            // keys globally unique -> strict > is a total order.
            ulonglong2 q01 = *(const ulonglong2*)(wrow);
            ulonglong2 q23 = *(const ulonglong2*)(wrow + 2);
            u64 kA = q01.y > q01.x ? q01.y : q01.x;
            u64 kB = q23.y > q23.x ? q23.y : q23.x;
            u64 k0 = kB > kA ? kB : kA;
            winner = NPTS - 1 - (int)(unsigned)(k0 & 0xffffffffull);
            if (t == 0) wins[i] = winner;          // LDS only; drained next barrier
        }
        // epilogue: bulk-write fid and p_out (off the per-iteration critical path)
        __syncthreads();
        for (int i = t; i < NOUT; i += 256) {
            int w = wins[i];
            fid[b * NOUT + i] = b * NPTS + w;
            float* po = pout + (size_t)i * 3;
            po[0] = lx[w]; po[1] = ly[w]; po[2] = lz[w];
        }
    } else {
        // ---------------- GEMM: h = relu(BN(x @ W^T + b)), bf16 MFMA ----------------
        const int bid = blockIdx.x - BATCH;
        const int bm = bid >> 2;           // 512 M-tiles of 128
        const int bn = bid & 3;            // 4 N-tiles of 128
        short* As = (short*)smem;          // [128][LDA]
        short* Bs = As + 128 * LDA;        // [128][LDA] (W is [n][k] = B^T)

        const int wm = wv >> 1, wn = wv & 1;   // 2x2 waves, 64x64 each
        const int quad = lane >> 4, l16 = lane & 15;
        const int m0 = bm * 128, n0 = bn * 128;

        f32x4 acc[4][4];
        const f32x4 zero = {0.0f, 0.0f, 0.0f, 0.0f};
#pragma unroll
        for (int a = 0; a < 4; ++a)
#pragma unroll
            for (int bb = 0; bb < 4; ++bb) acc[a][bb] = zero;

        const int srow = t >> 3;           // 0..31
        const int scol = (t & 7) << 2;     // 0..28

        for (int ks = 0; ks < 8; ++ks) {   // K=256 in steps of 32
            const int k0 = ks * 32;
            __syncthreads();
#pragma unroll
            for (int it = 0; it < 4; ++it) {
                int row = srow + it * 32;
                float4 va = *(const float4*)(x + (size_t)(m0 + row) * CIN + k0 + scol);
                short4 pa = make_short4((short)f2bf_rne(va.x), (short)f2bf_rne(va.y),
                                        (short)f2bf_rne(va.z), (short)f2bf_rne(va.w));
                *(short4*)(As + row * LDA + scol) = pa;
                float4 vb = *(const float4*)(W + (size_t)(n0 + row) * CIN + k0 + scol);
                short4 pb2 = make_short4((short)f2bf_rne(vb.x), (short)f2bf_rne(vb.y),
                                         (short)f2bf_rne(vb.z), (short)f2bf_rne(vb.w));
                *(short4*)(Bs + row * LDA + scol) = pb2;
            }
            __syncthreads();
            bf16x8 af[4], bfr[4];
#pragma unroll
            for (int tm = 0; tm < 4; ++tm)
                af[tm] = *(const bf16x8*)(As + (wm * 64 + tm * 16 + l16) * LDA + quad * 8);
#pragma unroll
            for (int tn = 0; tn < 4; ++tn)
                bfr[tn] = *(const bf16x8*)(Bs + (wn * 64 + tn * 16 + l16) * LDA + quad * 8);
#pragma unroll
            for (int tm = 0; tm < 4; ++tm)
#pragma unroll
                for (int tn = 0; tn < 4; ++tn)
                    acc[tm][tn] = __builtin_amdgcn_mfma_f32_16x16x32_bf16(
                        af[tm], bfr[tn], acc[tm][tn], 0, 0, 0);
        }
#pragma unroll
        for (int tn = 0; tn < 4; ++tn) {
            int c = n0 + wn * 64 + tn * 16 + l16;
            float sc = gamma[c] / sqrtf(rvar[c] + 1e-5f);
            float sh = (bias[c] - rmean[c]) * sc + beta[c];
#pragma unroll
            for (int tm = 0; tm < 4; ++tm) {
                int rbase = m0 + wm * 64 + tm * 16 + quad * 4;
#pragma unroll
                for (int r = 0; r < 4; ++r) {
                    float v = fmaxf(acc[tm][tn][r] * sc + sh, 0.0f);
                    h[(size_t)(rbase + r) * COUT + c] = f2bf_rne(v);
                }
            }
        }
    }
}

// Kernel 2: gather+maxpool — R8: ONE WAVE per output point, 16 B/lane loads.
// A wave's 64 lanes x 16 B = exactly one 1 KB h-row per load instruction
// (perfect coalescing, G13); 16 independent row-loads in flight per wave.
extern "C" __global__ void __launch_bounds__(64)
gather_maxpool(const int* __restrict__ sid32, const int* __restrict__ fid,
               const unsigned short* __restrict__ h, float* __restrict__ out)
{
    const int j = blockIdx.x;     // 0..16383
    const int t = threadIdx.x;    // 0..63
    __shared__ int rows[KNN];
    const int frow = fid[j];
    // sid_euc may be int32 or int64 (JAX x64 ambiguity); sniff high words.
    bool is64 = (sid32[1] == 0) && (sid32[3] == 0) && (sid32[5] == 0);
    if (t < KNN) {
        long long e = (long long)frow * KNN + t;
        rows[t] = is64 ? sid32[e * 2] : sid32[e];
    }
    __syncthreads();

    const int c8 = t << 3;        // 8 cols per lane, 64 lanes = 512 cols
    float m[8];
#pragma unroll
    for (int q = 0; q < 8; ++q) m[q] = -3.4028235e38f;
#pragma unroll
    for (int k = 0; k < KNN; ++k) {
        const u16x8 v = *(const u16x8*)(h + (size_t)rows[k] * COUT + c8);
#pragma unroll
        for (int q = 0; q < 8; ++q) m[q] = fmaxf(m[q], bf2f(v[q]));
    }
    float* po = out + (size_t)j * COUT + c8;
    *(float4*)(po)     = make_float4(m[0], m[1], m[2], m[3]);
    *(float4*)(po + 4) = make_float4(m[4], m[5], m[6], m[7]);
}

extern "C" void kernel_launch(void* const* d_in, const int* in_sizes, int n_in,
                              void* d_out, int out_size, void* d_ws, size_t ws_size,
                              hipStream_t stream)
{
    const float* x     = (const float*)d_in[0];
    const float* p     = (const float*)d_in[1];
    const int*   sid   = (const int*)d_in[2];   // tid_euc (d_in[3]) unused
    const float* W     = (const float*)d_in[4];
    const float* bias  = (const float*)d_in[5];
    const float* gamma = (const float*)d_in[6];
    const float* beta  = (const float*)d_in[7];
    const float* rmean = (const float*)d_in[8];
    const float* rvar  = (const float*)d_in[9];
    float* out = (float*)d_out;

    int* fid = (int*)d_ws;                                      // [16384] @ 0
    unsigned short* h = (unsigned short*)((char*)d_ws + 65792); // 65536x512 bf16

    hipLaunchKernelGGL(fps_gemm, dim3(BATCH + 2048), dim3(256), DYN_LDS, stream,
                       x, p, W, bias, gamma, beta, rmean, rvar, fid, h, out);
    hipLaunchKernelGGL(gather_maxpool, dim3(BATCH * NOUT), dim3(64), 0, stream,
                       sid, fid, h, out);
}